// Round 5
// baseline (3051.827 us; speedup 1.0000x reference)
//
#include <hip/hip_runtime.h>
#include <stdint.h>

// Problem dims
#define BATCH 128
#define SEQ   512
#define DIN   256
#define HID   512
#define NWG   256    // 4 groups x 64 WGs; 1 WG/CU
#define TPB   512    // 8 waves = (m 0..1) x (kq 0..3)
#define NSLOT 513
#define OUTD  1275
#define HSLOTF (BATCH * HID)   // floats per h slot (256 KB)

// workspace layout
#define WS_FLAGS 0                         // 4 groups x 64 u32 progress flags
#define WS_H0R   4096                      // 4 x 256KB fp32 h0 ring
#define WS_H1R   (4096 + 1048576)          // 4 x 256KB fp32 h1 ring
#define WS_H1FIN (4096 + 2097152)          // 256KB f32
#define WS_XB    (4096 + 2097152 + 262144) // 32MB
#define WS_MSET  (4096 + 2097152)          // memset: flags + both rings

typedef __attribute__((ext_vector_type(8))) short bf16x8;
typedef __attribute__((ext_vector_type(4))) float f32x4;

static __device__ __forceinline__ unsigned short f2bf(float f) {
  unsigned int u = __builtin_bit_cast(unsigned int, f);
  u += 0x7FFFu + ((u >> 16) & 1u);  // RNE
  return (unsigned short)(u >> 16);
}
static __device__ __forceinline__ float sigmoidf_fast(float v) {
  float e = __expf(-fabsf(v));
  float s = 1.0f / (1.0f + e);
  return v >= 0.0f ? s : 1.0f - s;
}
static __device__ __forceinline__ float tanhf_fast(float v) {
  float e = __expf(-2.0f * fabsf(v));
  float t = (1.0f - e) / (1.0f + e);
  return v >= 0.0f ? t : -t;
}

// Fabric (device-scope) ops: sc0 sc1 bypass L1+L2. The ONLY coherence
// primitive this kernel relies on is per-dword store/load atomicity at the
// coherence point — no placement, no ordering, no flush assumptions.
static __device__ __forceinline__ void ldg_nc_dw(unsigned int& d, const unsigned int* p) {
  asm volatile("global_load_dword %0, %1, off sc0 sc1" : "=v"(d) : "v"(p));
}
static __device__ __forceinline__ void ldg_nc_f4(f32x4& d, const float* p) {
  asm volatile("global_load_dwordx4 %0, %1, off sc0 sc1" : "=v"(d) : "v"(p));
}
static __device__ __forceinline__ void stg_nc4(unsigned int* p, unsigned int v) {
  asm volatile("global_store_dword %0, %1, off sc0 sc1" :: "v"(p), "v"(v) : "memory");
}
#define WAIT_TIE1(v) asm volatile("s_waitcnt vmcnt(0)" : "+v"(v) :: "memory")

// Poll all 64 progress flags >= thr; returns min (sticky ring guard).
static __device__ __forceinline__ int poll_min64(const unsigned int* base, int thr) {
  const unsigned int* fp = base + (threadIdx.x & 63);
  for (;;) {
    unsigned int v;
    ldg_nc_dw(v, fp);
    WAIT_TIE1(v);
    if (__ballot(v >= (unsigned int)thr) == ~0ull) {
      int mn = (int)v;
#pragma unroll
      for (int o = 1; o < 64; o <<= 1) { int t = __shfl_xor(mn, o, 64); mn = t < mn ? t : mn; }
      return mn;
    }
    __builtin_amdgcn_s_sleep(1);
  }
}

// Stamped-data poll: fragments are fp32 h-values whose low 10 mantissa bits
// carry (slot+1). Phase 1: canary (dword 0 of each frag's q-block, 16-way
// lane-shared address) until stamps match. Phase 2: full 8-float load per
// frag; EVERY dword's stamp is checked — this is the soundness, the canary
// is only a traffic filter. Convert to bf16 MFMA A-frags on success.
template <int N>
static __device__ __forceinline__ void pollcvt(const float* a0, const float* cb,
                                               unsigned tgt, bf16x8* out) {
  f32x4 lo[N], hi[N];
  for (;;) {
    // ---- canary ----
    {
      unsigned c[N];
#pragma unroll
      for (int i = 0; i < N; ++i)
        ldg_nc_dw(c[i], (const unsigned int*)(cb + (size_t)i * 512));
      if constexpr (N == 4) {
        asm volatile("s_waitcnt vmcnt(0)"
          : "+v"(c[0]), "+v"(c[1]), "+v"(c[2]), "+v"(c[3]) :: "memory");
      } else if constexpr (N == 6) {
        asm volatile("s_waitcnt vmcnt(0)"
          : "+v"(c[0]), "+v"(c[1]), "+v"(c[2]), "+v"(c[3]), "+v"(c[4]), "+v"(c[5])
          :: "memory");
      } else {
        asm volatile("s_waitcnt vmcnt(0)"
          : "+v"(c[0]), "+v"(c[1]), "+v"(c[2]), "+v"(c[3]),
            "+v"(c[4]), "+v"(c[5]), "+v"(c[6]), "+v"(c[7]) :: "memory");
      }
      unsigned acc = 0;
#pragma unroll
      for (int i = 0; i < N; ++i) acc |= c[i] ^ tgt;
      if (__ballot((acc & 1023u) == 0u) != ~0ull) {
        __builtin_amdgcn_s_sleep(2);
        continue;
      }
    }
    // ---- full load + total stamp check ----
#pragma unroll
    for (int i = 0; i < N; ++i) {
      ldg_nc_f4(lo[i], a0 + (size_t)i * 512);
      ldg_nc_f4(hi[i], a0 + (size_t)i * 512 + 4);
    }
    if constexpr (N == 4) {
      asm volatile("s_waitcnt vmcnt(0)"
        : "+v"(lo[0]), "+v"(lo[1]), "+v"(lo[2]), "+v"(lo[3]),
          "+v"(hi[0]), "+v"(hi[1]), "+v"(hi[2]), "+v"(hi[3]) :: "memory");
    } else if constexpr (N == 6) {
      asm volatile("s_waitcnt vmcnt(0)"
        : "+v"(lo[0]), "+v"(lo[1]), "+v"(lo[2]), "+v"(lo[3]), "+v"(lo[4]), "+v"(lo[5]),
          "+v"(hi[0]), "+v"(hi[1]), "+v"(hi[2]), "+v"(hi[3]), "+v"(hi[4]), "+v"(hi[5])
        :: "memory");
    } else {
      asm volatile("s_waitcnt vmcnt(0)"
        : "+v"(lo[0]), "+v"(lo[1]), "+v"(lo[2]), "+v"(lo[3]),
          "+v"(lo[4]), "+v"(lo[5]), "+v"(lo[6]), "+v"(lo[7]),
          "+v"(hi[0]), "+v"(hi[1]), "+v"(hi[2]), "+v"(hi[3]),
          "+v"(hi[4]), "+v"(hi[5]), "+v"(hi[6]), "+v"(hi[7]) :: "memory");
    }
    unsigned acc = 0;
#pragma unroll
    for (int i = 0; i < N; ++i)
#pragma unroll
      for (int j = 0; j < 4; ++j) {
        acc |= __builtin_bit_cast(unsigned, lo[i][j]) ^ tgt;
        acc |= __builtin_bit_cast(unsigned, hi[i][j]) ^ tgt;
      }
    if (__ballot((acc & 1023u) == 0u) == ~0ull) break;
    __builtin_amdgcn_s_sleep(1);
  }
#pragma unroll
  for (int i = 0; i < N; ++i) {
    bf16x8 v;
#pragma unroll
    for (int j = 0; j < 4; ++j) {
      v[j]     = (short)f2bf(lo[i][j]);
      v[4 + j] = (short)f2bf(hi[i][j]);
    }
    out[i] = v;
  }
}

// x -> bf16 MFMA-fragment order: xb[(((p*8+mi)*8+kt)*64+lane)*8]
__global__ __launch_bounds__(256) void xprep(const float* __restrict__ x,
                                             unsigned short* __restrict__ xb) {
  int p = blockIdx.x;
  int lane = threadIdx.x & 63;
  int g4 = threadIdx.x >> 6;
  int c15 = lane & 15, q = lane >> 4;
  for (int g = 0; g < 16; ++g) {
    int idx = g * 4 + g4;  // (mi,kt)
    int mi = idx >> 3, kt = idx & 7;
    int row = mi * 16 + c15;
    const float* src = x + ((size_t)row * SEQ + p) * DIN + kt * 32 + q * 8;
    f32x4 a = *(const f32x4*)src;
    f32x4 b = *(const f32x4*)(src + 4);
    bf16x8 v;
    v[0] = (short)f2bf(a[0]); v[1] = (short)f2bf(a[1]);
    v[2] = (short)f2bf(a[2]); v[3] = (short)f2bf(a[3]);
    v[4] = (short)f2bf(b[0]); v[5] = (short)f2bf(b[1]);
    v[6] = (short)f2bf(b[2]); v[7] = (short)f2bf(b[3]);
    *(bf16x8*)&xb[((((size_t)p * 8 + mi) * 8 + kt) * 64 + lane) * 8] = v;
  }
}

// Persistent 2-layer LSTM, batch-split; stamp-certified dataflow.
// h rings are fp32 with a 10-bit (slot+1) stamp in the low mantissa bits:
// sync and data are the SAME dword, so the serial chain per slot is just
// producer-store -> visibility -> consumer stamp-poll -> MFMA. No producer
// drain, no flags, no barriers on the chain; per-wave independent polling.
// Ring depth 4; reuse guarded by consumed-progress flags (sticky, off-chain).
// Rings memset each launch => stale (incl. cross-run) stamps never match.
template <bool USE_XB>
__global__ __launch_bounds__(TPB, 1) void lstm_persistent(
    const float* __restrict__ x, const unsigned short* __restrict__ xb,
    const float* __restrict__ W0, const float* __restrict__ b0,
    const float* __restrict__ W1, const float* __restrict__ b1,
    unsigned int* __restrict__ prog, float* __restrict__ h0r,
    float* __restrict__ h1r, float* __restrict__ h1fin)
{
  __shared__ unsigned short sWf[4 * 32 * 64 * 8];  // 128 KB B-frags [ct][kt][lane][8]
  __shared__ float red[4 * 32 * 33];               // 16.9 KB padded partials

  const int tid  = threadIdx.x;
  const int wgid = blockIdx.x;
  const int g    = wgid >> 6;          // group 0..3 (batch rows 32g..32g+31)
  const int r    = wgid & 63;          // role in group
  const bool isA = (r < 32);
  const int unit0 = (isA ? r : r - 32) << 4;  // 16 units per WG
  const int lane = tid & 63;
  const int wv   = tid >> 6;
  const int m    = wv & 1;             // M-tile within group (16 rows)
  const int kq   = wv >> 1;            // K-quarter 0..3
  const int c15  = lane & 15;
  const int q    = lane >> 4;
  const int miG  = g * 2 + m;          // global M-tile
  const int KT   = isA ? 24 : 32;

  // ---- one-time: weights -> LDS fragment layout; col c = u_local*4 + gate ----
  {
    const float* W = isA ? W0 : W1;
    for (int f = tid; f < 4 * KT * 64; f += TPB) {
      int ct = f / (KT * 64);
      int rem = f - ct * (KT * 64);
      int kt = rem >> 6, ln = rem & 63;
      int qq = ln >> 4, cc = ln & 15;
      int u_local = ct * 4 + (cc >> 2);
      int gate = cc & 3;
      int gcol = gate * HID + unit0 + u_local;
      int kbase = kt * 32 + qq * 8;
      bf16x8 v;
#pragma unroll
      for (int j = 0; j < 8; ++j)
        v[j] = (short)f2bf(W[(size_t)(kbase + j) * 2048 + gcol]);
      *(bf16x8*)&sWf[(size_t)f * 8] = v;
    }
  }

  // gate-thread state (tid<256): thread = (row grow_, unit gu) x 2 chunks
  const int grow_ = tid >> 3, gu = tid & 7;
  float bias_c[2][4];
  float cst[2] = {0.f, 0.f};
  size_t hoff[2] = {0, 0};
  if (tid < 256) {
    const float* bv = isA ? b0 : b1;
#pragma unroll
    for (int ch = 0; ch < 2; ++ch) {
#pragma unroll
      for (int gt = 0; gt < 4; ++gt)
        bias_c[ch][gt] = bv[gt * HID + unit0 + ch * 8 + gu];
      int U = unit0 + ch * 8 + gu;
      int mi = g * 2 + (grow_ >> 4), r15g = grow_ & 15;
      hoff[ch] = ((size_t)(mi * 16 + (U >> 5)) * 64 + ((U & 31) >> 3) * 16 + r15g) * 8 + gu;
    }
  }
  __syncthreads();

  unsigned int* progF = prog + g * 64;

#define BFRAG(ct, kt) (*(const bf16x8*)&sWf[((((ct) * KT + (kt)) << 6) + lane) << 3])

  int guardSeen = 0;  // sticky ring-guard horizon (wave0)

  for (int p = 0; p < NSLOT; ++p) {
    // ring depth 4: h(s) at idx s&3. Read h(p-1) at (p+3)&3; write h(p) at p&3.
    const float* h0rd = h0r + (size_t)((p + 3) & 3) * HSLOTF;
    float*       h0wr = h0r + (size_t)(p & 3) * HSLOTF;
    const float* h1rd = h1r + (size_t)((p + 3) & 3) * HSLOTF;
    float*       h1wr = h1r + (size_t)(p & 3) * HSLOTF;
    const bool active = isA ? (p < SEQ) : (p >= 1);
    const unsigned tgt = (unsigned)p;   // stamp of h(p-1) is (p-1)+1 = p

    f32x4 acc[4];
#pragma unroll
    for (int ct = 0; ct < 4; ++ct) acc[ct] = (f32x4){0.f, 0.f, 0.f, 0.f};

    // ---- ring guard (wave0, sticky, off-chain): before slot-p ring stores
    // (which overwrite h(p-4)), all 64 group WGs must have finished slot p-3
    // (progress >= p-2). Ordered before gates' stores by the ch-loop barrier.
    if (wv == 0 && p > 3 && guardSeen < p - 2)
      guardSeen = poll_min64(progF, p - 2);

    // ---- L0 x-part (kt<8 of my K-quarter), independent of recurrence ----
    if (isA && active) {
      int ktlo = kq * 6, kthi = ktlo + 6;
      for (int kt = ktlo; kt < kthi && kt < 8; ++kt) {
        bf16x8 ax;
        if (USE_XB) {
          ax = *(const bf16x8*)&xb[((((size_t)p * 8 + miG) * 8 + kt) * 64 + lane) * 8];
        } else {
          const float* xp0 = x + (((size_t)(miG * 16 + c15)) * SEQ + p) * DIN + kt * 32 + q * 8;
          f32x4 a = *(const f32x4*)xp0;
          f32x4 b = *(const f32x4*)(xp0 + 4);
          ax[0] = (short)f2bf(a[0]); ax[1] = (short)f2bf(a[1]);
          ax[2] = (short)f2bf(a[2]); ax[3] = (short)f2bf(a[3]);
          ax[4] = (short)f2bf(b[0]); ax[5] = (short)f2bf(b[1]);
          ax[6] = (short)f2bf(b[2]); ax[7] = (short)f2bf(b[3]);
        }
#pragma unroll
        for (int ct = 0; ct < 4; ++ct)
          acc[ct] = __builtin_amdgcn_mfma_f32_16x16x32_bf16(ax, BFRAG(ct, kt), acc[ct], 0, 0, 0);
      }
    }

    // ---- per-wave stamped data acquisition + dependent MFMA ----
    if (active) {
      if (isA) {
        if (p > 0 && kq == 1) {        // h0 frags 0..3 -> kt 8..11
          bf16x8 ah[4];
          const float* a0 = h0rd + ((size_t)(miG * 16 + 0) * 64 + lane) * 8;
          const float* cb = h0rd + ((size_t)(miG * 16 + 0) * 64 + q * 16) * 8;
          pollcvt<4>(a0, cb, tgt, ah);
#pragma unroll
          for (int i = 0; i < 4; ++i)
#pragma unroll
            for (int ct = 0; ct < 4; ++ct)
              acc[ct] = __builtin_amdgcn_mfma_f32_16x16x32_bf16(ah[i], BFRAG(ct, 8 + i), acc[ct], 0, 0, 0);
        } else if (p > 0 && kq >= 2) { // h0 frags 4..9 / 10..15 -> kt 12..23
          bf16x8 ah[6];
          int f0 = kq * 6 - 8;
          const float* a0 = h0rd + ((size_t)(miG * 16 + f0) * 64 + lane) * 8;
          const float* cb = h0rd + ((size_t)(miG * 16 + f0) * 64 + q * 16) * 8;
          pollcvt<6>(a0, cb, tgt, ah);
#pragma unroll
          for (int i = 0; i < 6; ++i)
#pragma unroll
            for (int ct = 0; ct < 4; ++ct)
              acc[ct] = __builtin_amdgcn_mfma_f32_16x16x32_bf16(ah[i], BFRAG(ct, kq * 6 + i), acc[ct], 0, 0, 0);
        }
      } else {
        if (kq < 2) {                  // h0 frags kq*8..+7 -> kt 0..15
          bf16x8 ah[8];
          const float* a0 = h0rd + ((size_t)(miG * 16 + kq * 8) * 64 + lane) * 8;
          const float* cb = h0rd + ((size_t)(miG * 16 + kq * 8) * 64 + q * 16) * 8;
          pollcvt<8>(a0, cb, tgt, ah);
#pragma unroll
          for (int i = 0; i < 8; ++i)
#pragma unroll
            for (int ct = 0; ct < 4; ++ct)
              acc[ct] = __builtin_amdgcn_mfma_f32_16x16x32_bf16(ah[i], BFRAG(ct, kq * 8 + i), acc[ct], 0, 0, 0);
        } else if (p > 1) {            // h1 frags (kq-2)*8..+7 -> kt 16..31
          bf16x8 ah[8];
          const float* a0 = h1rd + ((size_t)(miG * 16 + (kq - 2) * 8) * 64 + lane) * 8;
          const float* cb = h1rd + ((size_t)(miG * 16 + (kq - 2) * 8) * 64 + q * 16) * 8;
          pollcvt<8>(a0, cb, tgt, ah);
#pragma unroll
          for (int i = 0; i < 8; ++i)
#pragma unroll
            for (int ct = 0; ct < 4; ++ct)
              acc[ct] = __builtin_amdgcn_mfma_f32_16x16x32_bf16(ah[i], BFRAG(ct, kq * 8 + i), acc[ct], 0, 0, 0);
        }
      }
    }

    // ---- cross-wave K-reduce + gates; gates store stamped h directly ----
#pragma unroll
    for (int ch = 0; ch < 2; ++ch) {
      __syncthreads();
      if (active) {
        int lrow = m * 16 + q * 4;
#pragma unroll
        for (int t = 0; t < 2; ++t)
#pragma unroll
          for (int rr = 0; rr < 4; ++rr)
            red[(kq * 32 + lrow + rr) * 33 + t * 16 + c15] = acc[ch * 2 + t][rr];
      }
      __syncthreads();
      if (active && tid < 256) {
        float z[4];
#pragma unroll
        for (int gt = 0; gt < 4; ++gt) {
          float s = bias_c[ch][gt];
          int cidx = gu * 4 + gt;
#pragma unroll
          for (int k2 = 0; k2 < 4; ++k2)
            s += red[(k2 * 32 + grow_) * 33 + cidx];
          z[gt] = s;
        }
        float cn = sigmoidf_fast(z[1]) * cst[ch] + sigmoidf_fast(z[0]) * tanhf_fast(z[2]);
        cst[ch] = cn;
        float hn = sigmoidf_fast(z[3]) * tanhf_fast(cn);
        // stamp low 10 mantissa bits with (p+1); fire-and-forget publish
        unsigned hb = (__builtin_bit_cast(unsigned, hn) & ~1023u) | (unsigned)(p + 1);
        stg_nc4((unsigned int*)((isA ? h0wr : h1wr) + hoff[ch]), hb);
        if (!isA && p == NSLOT - 1)
          h1fin[(size_t)(g * 32 + grow_) * HID + unit0 + ch * 8 + gu] = hn;
      }
    }

    // ---- progress (consumed) flag: after ch=1's barriers all waves' loads
    // of slot p are complete; no drain needed (certifies reads, not writes).
    if (tid == 0) stg_nc4(progF + r, (unsigned int)(p + 1));
    // no trailing barrier: next slot's first reduce barrier rejoins waves
  }
#undef BFRAG
}

__global__ __launch_bounds__(256) void proj_kernel(
    const float* __restrict__ h1, const float* __restrict__ Wp,
    const float* __restrict__ bp, float* __restrict__ out)
{
  int o = blockIdx.x * 256 + threadIdx.x;
  int b = blockIdx.y;
  if (o >= OUTD) return;
  const float* hr = h1 + (size_t)b * HID;
  float acc = bp[o];
#pragma unroll 8
  for (int k = 0; k < HID; ++k)
    acc = fmaf(hr[k], Wp[(size_t)k * OUTD + o], acc);
  out[(size_t)b * OUTD + o] = acc;
}

extern "C" void kernel_launch(void* const* d_in, const int* in_sizes, int n_in,
                              void* d_out, int out_size, void* d_ws, size_t ws_size,
                              hipStream_t stream) {
  const float* x  = (const float*)d_in[0];
  const float* W0 = (const float*)d_in[1];
  const float* b0 = (const float*)d_in[2];
  const float* W1 = (const float*)d_in[3];
  const float* b1 = (const float*)d_in[4];
  const float* Wp = (const float*)d_in[5];
  const float* bp = (const float*)d_in[6];
  float* out = (float*)d_out;

  char* ws = (char*)d_ws;
  unsigned int* prog  = (unsigned int*)(ws + WS_FLAGS);
  float* h0r          = (float*)(ws + WS_H0R);
  float* h1r          = (float*)(ws + WS_H1R);
  float* h1fin        = (float*)(ws + WS_H1FIN);
  unsigned short* xbp = (unsigned short*)(ws + WS_XB);
  const size_t need_xb = (size_t)WS_XB + (size_t)SEQ * BATCH * DIN * 2;
  const bool use_xb = (ws_size >= need_xb);

  // Zero flags + rings: stamp 0 never matches a target (targets are >= 1),
  // which also kills cross-run stamp aliasing.
  hipMemsetAsync(d_ws, 0, WS_MSET, stream);
  if (use_xb) {
    hipLaunchKernelGGL(xprep, dim3(SEQ), dim3(256), 0, stream, x, xbp);
    hipLaunchKernelGGL(lstm_persistent<true>, dim3(NWG), dim3(TPB), 0, stream,
                       x, xbp, W0, b0, W1, b1, prog, h0r, h1r, h1fin);
  } else {
    hipLaunchKernelGGL(lstm_persistent<false>, dim3(NWG), dim3(TPB), 0, stream,
                       x, xbp, W0, b0, W1, b1, prog, h0r, h1r, h1fin);
  }
  hipLaunchKernelGGL(proj_kernel, dim3((OUTD + 255) / 256, BATCH), dim3(256), 0, stream,
                     h1fin, Wp, bp, out);
}